// Round 2
// baseline (726.677 us; speedup 1.0000x reference)
//
#include <hip/hip_runtime.h>
#include <hip/hip_bf16.h>

// Single-head causal attention, B=16, T=2048, D=H=1024.
// Pipeline: cvt x->f16 (into d_out lo) | transpose W->f16 | Q GEMM (ws) |
//   K GEMM (into d_out hi) | Vt GEMM (ws) | per-batch-chunk:
//   S=QK^T (tri, f16) -> softmax (in-place f16) -> O = P @ V^T -> d_out (f32).
// d_out doubles as scratch for x16/K; PV overwrites it only after the QK^T
// pass that consumed the aliased K batches (stream order makes this safe).
// Workspace use: 6MB weights + 67MB Q + 67MB Vt + NB*8.4MB S-chunk (NB<=16).

typedef _Float16 half8 __attribute__((ext_vector_type(8)));
typedef _Float16 half4v __attribute__((ext_vector_type(4)));
typedef float floatx4 __attribute__((ext_vector_type(4)));

#define TB 16
#define TT 2048
#define TD 1024

// ---------------- convert x fp32 -> fp16 ----------------
__global__ void cvt_f32_f16(const float* __restrict__ in, _Float16* __restrict__ out, long n) {
    long i = ((long)blockIdx.x * blockDim.x + threadIdx.x) * 4;
    long stride = (long)gridDim.x * blockDim.x * 4;
    for (; i < n; i += stride) {
        float4 f = *(const float4*)(in + i);
        half4v h;
        h[0] = (_Float16)f.x; h[1] = (_Float16)f.y;
        h[2] = (_Float16)f.z; h[3] = (_Float16)f.w;
        *(half4v*)(out + i) = h;
    }
}

// ---------------- transpose + convert W [1024,1024] ----------------
__global__ void transpose_cvt_w(const float* __restrict__ in, _Float16* __restrict__ out) {
    __shared__ float tile[32][33];
    const int bx = blockIdx.x * 32, by = blockIdx.y * 32;
    const int tx = threadIdx.x, ty = threadIdx.y; // block 32x8
#pragma unroll
    for (int i = ty; i < 32; i += 8) tile[i][tx] = in[(long)(by + i) * 1024 + bx + tx];
    __syncthreads();
#pragma unroll
    for (int i = ty; i < 32; i += 8) out[(long)(bx + i) * 1024 + by + tx] = (_Float16)tile[tx][i];
}

// ---------------- unified BT GEMM ----------------
// C[i,j] = sum_k A[i,k]*B[j,k];  A:[M,K] f16 row-major (lda), B:[N,K] f16 row-major (ldb)
// MODE 0: f16 out, plain grid (ti=bx/tilesN)
// MODE 1: f16 out, lower-triangular tile grid (S = Q K^T)
// MODE 2: f32 out, plain grid, K-loop trimmed to (ti+1)*128 (O = P V^T, causal)
__device__ __forceinline__ void gload16(const _Float16* g, _Float16* l) {
    __builtin_amdgcn_global_load_lds((const __attribute__((address_space(1))) void*)g,
                                     (__attribute__((address_space(3))) void*)l, 16, 0, 0);
}

template <int MODE>
__global__ __launch_bounds__(256) void gemm_bt(const _Float16* __restrict__ A,
                                               const _Float16* __restrict__ B,
                                               void* __restrict__ Cout,
                                               int K, int lda, int ldb, int ldc,
                                               long sAb, long sBb, long sCb, int tilesN) {
    __shared__ _Float16 As[128 * 64];
    __shared__ _Float16 Bs[128 * 64];
    const int tid = threadIdx.x, lane = tid & 63, w = tid >> 6;
    const int wr = w >> 1, wc = w & 1;

    int ti, tj;
    if (MODE == 1) {
        int r = blockIdx.x; ti = 0;
        while (r > ti) { r -= ti + 1; ++ti; }
        tj = r;
    } else {
        ti = blockIdx.x / tilesN; tj = blockIdx.x % tilesN;
    }
    const int b = blockIdx.y;
    A += (long)b * sAb;
    B += (long)b * sBb;
    const long m0 = (long)ti * 128, n0 = (long)tj * 128;
    const int nkt = (MODE == 2) ? (ti + 1) * 2 : (K >> 6);

    floatx4 acc[4][4] = {};

    for (int kt = 0; kt < nkt; ++kt) {
        const int k0 = kt * 64;
        // stage A & B tiles: each wave stages 32 rows of each, 4 insts x (8 rows/inst)
        const int rb = w * 32;
#pragma unroll
        for (int i = 0; i < 4; ++i) {
            const int rt = rb + i * 8;
            const int rr = rt + (lane >> 3);
            const int cc8 = k0 + (lane & 7) * 8;
            gload16(A + (m0 + rr) * (long)lda + cc8, &As[rt * 64]);
            gload16(B + (n0 + rr) * (long)ldb + cc8, &Bs[rt * 64]);
        }
        __syncthreads();
#pragma unroll
        for (int kk = 0; kk < 2; ++kk) {
            half8 af[4], bf[4];
            const int kof = kk * 32 + (lane >> 4) * 8;
#pragma unroll
            for (int m = 0; m < 4; ++m)
                af[m] = *(const half8*)&As[(wr * 64 + m * 16 + (lane & 15)) * 64 + kof];
#pragma unroll
            for (int n = 0; n < 4; ++n)
                bf[n] = *(const half8*)&Bs[(wc * 64 + n * 16 + (lane & 15)) * 64 + kof];
#pragma unroll
            for (int m = 0; m < 4; ++m)
#pragma unroll
                for (int n = 0; n < 4; ++n)
                    acc[m][n] = __builtin_amdgcn_mfma_f32_16x16x32_f16(af[m], bf[n], acc[m][n], 0, 0, 0);
        }
        __syncthreads();
    }

    // epilogue: C/D layout col=lane&15, row=(lane>>4)*4+j
    const int r4 = (lane >> 4) * 4, cc = lane & 15;
    if (MODE <= 1) {
        _Float16* C = (_Float16*)Cout + (long)b * sCb;
#pragma unroll
        for (int m = 0; m < 4; ++m) {
            const long rbase = m0 + wr * 64 + m * 16 + r4;
#pragma unroll
            for (int n = 0; n < 4; ++n) {
                const long cbase = n0 + wc * 64 + n * 16 + cc;
#pragma unroll
                for (int j = 0; j < 4; ++j)
                    C[(rbase + j) * (long)ldc + cbase] = (_Float16)acc[m][n][j];
            }
        }
    } else {
        float* C = (float*)Cout + (long)b * sCb;
#pragma unroll
        for (int m = 0; m < 4; ++m) {
            const long rbase = m0 + wr * 64 + m * 16 + r4;
#pragma unroll
            for (int n = 0; n < 4; ++n) {
                const long cbase = n0 + wc * 64 + n * 16 + cc;
#pragma unroll
                for (int j = 0; j < 4; ++j)
                    C[(rbase + j) * (long)ldc + cbase] = acc[m][n][j];
            }
        }
    }
}

// ---------------- row softmax, causal, in-place f16 ----------------
__device__ __forceinline__ float blockReduce(float v, bool ismax, float* sb) {
#pragma unroll
    for (int o = 32; o; o >>= 1) {
        float t = __shfl_xor(v, o);
        v = ismax ? fmaxf(v, t) : v + t;
    }
    if ((threadIdx.x & 63) == 0) sb[threadIdx.x >> 6] = v;
    __syncthreads();
    v = ismax ? fmaxf(fmaxf(sb[0], sb[1]), fmaxf(sb[2], sb[3]))
              : (sb[0] + sb[1]) + (sb[2] + sb[3]);
    __syncthreads();
    return v;
}

__global__ __launch_bounds__(256) void softmax_rows_f16(_Float16* __restrict__ S, int T) {
    __shared__ float sb[4];
    const long row = blockIdx.x; // (chunk-local b)*T + t
    const int t = (int)(row % T);
    _Float16* s = S + row * (long)T;
    const int tid = threadIdx.x;

    half8 hv = *(const half8*)(s + tid * 8);
    float v[8];
    float mx = -__builtin_inff();
#pragma unroll
    for (int j = 0; j < 8; ++j) {
        const int col = tid * 8 + j;
        v[j] = (col <= t) ? (float)hv[j] : -__builtin_inff();
        mx = fmaxf(mx, v[j]);
    }
    const float m = blockReduce(mx, true, sb);

    float sum = 0.f;
#pragma unroll
    for (int j = 0; j < 8; ++j) {
        float p = __expf(v[j] - m); // exp(-inf) = 0 handles the mask
        v[j] = p;
        sum += p;
    }
    const float l = blockReduce(sum, false, sb);
    const float inv = 1.f / l;

    half8 o;
#pragma unroll
    for (int j = 0; j < 8; ++j) o[j] = (_Float16)(v[j] * inv);
    *(half8*)(s + tid * 8) = o;
}

// ---------------- launch ----------------
extern "C" void kernel_launch(void* const* d_in, const int* in_sizes, int n_in,
                              void* d_out, int out_size, void* d_ws, size_t ws_size,
                              hipStream_t stream) {
    const float* x  = (const float*)d_in[0];
    const float* Wq = (const float*)d_in[1];
    const float* Wk = (const float*)d_in[2];
    const float* Wv = (const float*)d_in[3];
    float* out = (float*)d_out;

    const size_t XB = (size_t)TB * TT * TD; // 33.5M elems

    // scratch aliased into d_out (134.2 MB): x16 lo half, K hi half.
    // Both fully dead by the time the PV pass overwrites their bytes.
    _Float16* x16 = (_Float16*)d_out;
    _Float16* Kh  = (_Float16*)d_out + XB;

    // workspace carve-up (bytes, 256-aligned)
    char* ws = (char*)d_ws;
    size_t off = 0;
    auto carve = [&](size_t bytes) { char* p = ws + off; off = (off + bytes + 255) & ~(size_t)255; return p; };
    _Float16* wqt = (_Float16*)carve((size_t)TD * TD * 2);
    _Float16* wkt = (_Float16*)carve((size_t)TD * TD * 2);
    _Float16* wvt = (_Float16*)carve((size_t)TD * TD * 2);
    _Float16* Qh  = (_Float16*)carve(XB * 2);                 // [B][T][H]
    _Float16* Vt  = (_Float16*)carve(XB * 2);                 // [B][H][T]

    const size_t CH = (size_t)TT * TT * 2;                    // 8.39 MB per batch
    int NB = 16;                                              // batches per S-chunk
    while (NB > 1 && off + (size_t)NB * CH > ws_size) NB >>= 1;
    _Float16* Sc = (_Float16*)carve((size_t)NB * CH);         // [NB][T][T] f16

    // 1. convert x -> f16 (into d_out lo)
    cvt_f32_f16<<<2048, 256, 0, stream>>>(x, x16, (long)XB);
    // 2. transpose+convert weights -> [H,D] f16
    transpose_cvt_w<<<dim3(32, 32), dim3(32, 8), 0, stream>>>(Wq, wqt);
    transpose_cvt_w<<<dim3(32, 32), dim3(32, 8), 0, stream>>>(Wk, wkt);
    transpose_cvt_w<<<dim3(32, 32), dim3(32, 8), 0, stream>>>(Wv, wvt);

    // 3. Q = x @ Wq : flat M=32768, N=1024, K=1024
    gemm_bt<0><<<dim3(256 * 8, 1), 256, 0, stream>>>(x16, wqt, Qh, TD, TD, TD, TD, 0, 0, 0, 8);
    // 4. K = x @ Wk -> d_out hi
    gemm_bt<0><<<dim3(256 * 8, 1), 256, 0, stream>>>(x16, wkt, Kh, TD, TD, TD, TD, 0, 0, 0, 8);
    // 5. Vt[b] = (x[b] @ Wv)^T : C[h,t] = sum_d wvt[h,d]*x16[t,d]
    gemm_bt<0><<<dim3(8 * 16, TB), 256, 0, stream>>>(wvt, x16, Vt, TD, TD, TD, TT,
                                                     0, (long)TT * TD, (long)TD * TT, 16);

    // 6. per chunk of NB batches: S -> softmax -> O
    for (int cb = 0; cb < TB; cb += NB) {
        // S[b] = Q[b] K[b]^T, lower-triangular tiles only (136/batch), f16 out
        gemm_bt<1><<<dim3(136, NB), 256, 0, stream>>>(Qh + (size_t)cb * TT * TD,
                                                      Kh + (size_t)cb * TT * TD, Sc,
                                                      TD, TD, TD, TT,
                                                      (long)TT * TD, (long)TT * TD, (long)TT * TT, 16);
        // softmax rows in-place (upper-tri reads masked -> stale bytes harmless)
        softmax_rows_f16<<<NB * TT, 256, 0, stream>>>(Sc, TT);
        // O[b] = P[b] @ V[b] : C[t,h] = sum_s P[t,s]*Vt[h,s]; causal K-trim
        gemm_bt<2><<<dim3(16 * 8, NB), 256, 0, stream>>>(Sc, Vt + (size_t)cb * TD * TT,
                                                         out + (size_t)cb * TT * TD, TT,
                                                         TT, TT, TD,
                                                         (long)TT * TT, (long)TD * TT, (long)TT * TD, 8);
    }
}

// Round 4
// 543.608 us; speedup vs baseline: 1.3368x; 1.3368x over previous
//
#include <hip/hip_runtime.h>
#include <hip/hip_bf16.h>

// Single-head causal attention, B=16, T=2048, D=H=1024.
// cvt x->f16 (d_out lo) | transpose W | Q GEMM (ws) | K GEMM (d_out hi) |
// Vt GEMM (ws) | per-chunk: S=QK^T (tri,f16) -> causal softmax (in-place) ->
// O = P@V^T -> d_out f32.
// GEMM: 256x256 tile, BK=64, 8 waves, 4-phase/K-tile schedule, counted vmcnt,
// swizzled LDS (k-major regions), global_load_lds x16B, XCD-bijective swizzle.
// FIX vs r3: last K-iter phase-1 wait must drain vmcnt(0) (no stages in
// flight behind the needed kk=1 data when pf=false) — was racing the DMA.

typedef _Float16 half8 __attribute__((ext_vector_type(8)));
typedef _Float16 half4v __attribute__((ext_vector_type(4)));
typedef float floatx4 __attribute__((ext_vector_type(4)));

#define TB 16
#define TT 2048
#define TD 1024

// ---------------- convert x fp32 -> fp16 ----------------
__global__ void cvt_f32_f16(const float* __restrict__ in, _Float16* __restrict__ out, long n) {
    long i = ((long)blockIdx.x * blockDim.x + threadIdx.x) * 4;
    long stride = (long)gridDim.x * blockDim.x * 4;
    for (; i < n; i += stride) {
        float4 f = *(const float4*)(in + i);
        half4v h;
        h[0] = (_Float16)f.x; h[1] = (_Float16)f.y;
        h[2] = (_Float16)f.z; h[3] = (_Float16)f.w;
        *(half4v*)(out + i) = h;
    }
}

// ---------------- transpose + convert W [1024,1024] ----------------
__global__ void transpose_cvt_w(const float* __restrict__ in, _Float16* __restrict__ out) {
    __shared__ float tile[32][33];
    const int bx = blockIdx.x * 32, by = blockIdx.y * 32;
    const int tx = threadIdx.x, ty = threadIdx.y; // block 32x8
#pragma unroll
    for (int i = ty; i < 32; i += 8) tile[i][tx] = in[(long)(by + i) * 1024 + bx + tx];
    __syncthreads();
#pragma unroll
    for (int i = ty; i < 32; i += 8) out[(long)(bx + i) * 1024 + by + tx] = (_Float16)tile[tx][i];
}

// ---------------- 256x256 8-wave 4-phase BT GEMM ----------------
// C[i,j] = sum_k A[i,k]*B[j,k]; A:[M,K] f16 (lda), B:[N,K] f16 (ldb)
// MODE 0: f16 out, plain grid. MODE 1: f16 out, lower-tri tile grid.
// MODE 2: f32 out, plain grid, ti reversed, K trimmed to (ti+1)*256.
__device__ __forceinline__ void gload16(const _Float16* g, _Float16* l) {
    __builtin_amdgcn_global_load_lds((const __attribute__((address_space(1))) void*)g,
                                     (__attribute__((address_space(3))) void*)l, 16, 0, 0);
}

template <int MODE>
__global__ __launch_bounds__(512, 2) void gemm256(const _Float16* __restrict__ A,
                                                  const _Float16* __restrict__ B,
                                                  void* __restrict__ Cout,
                                                  int K, int lda, int ldb, int ldc,
                                                  long sAb, long sBb, long sCb,
                                                  int tilesN, int tilesM) {
    // LDS: As regions [2buf][2kk][256][32] f16 (64KB) then Bs same (64KB).
    __shared__ _Float16 lds[65536];
    const int tid = threadIdx.x, lane = tid & 63, w = tid >> 6;
    const int wr = w >> 2, wc = w & 3;

    // XCD-bijective blockIdx swizzle (m204)
    int bx = blockIdx.x;
    {
        const int nwg = gridDim.x, q = nwg >> 3, r = nwg & 7;
        const int xcd = bx & 7, idx = bx >> 3;
        bx = (xcd < r ? xcd * (q + 1) : r * (q + 1) + (xcd - r) * q) + idx;
    }
    int ti, tj;
    if (MODE == 1) {
        int rd = bx; ti = 0;
        while (rd > ti) { rd -= ti + 1; ++ti; }
        tj = rd;
    } else {
        ti = bx / tilesN; tj = bx % tilesN;
        if (MODE == 2) ti = tilesM - 1 - ti; // big-K tiles first
    }
    const int b = blockIdx.y;
    A += (long)b * sAb;
    B += (long)b * sBb;
    const long m0 = (long)ti * 256, n0 = (long)tj * 256;
    const int nkt = (MODE == 2) ? (ti + 1) * 4 : (K >> 6);

    // staging: thread stages chunk q0=tid and q0+512 per (matrix, region).
    const int row0 = tid >> 2;                                  // 0..127 (+128 for 2nd load)
    const int co   = (((tid & 3) ^ ((tid >> 3) & 3)) << 3);     // inverse-swizzled f16 col
    // frag read: lane wants logical chunk (lane>>4); stored at chunk ^ ((row>>1)&3)
    const int fcol = ((((lane >> 4) ^ (lane >> 1)) & 3) << 3);
    const int arow = wr * 128 + (lane & 15);
    const int brow = wc * 64 + (lane & 15);

    auto Abase = [&](int buf, int kk) { return lds + ((buf * 2 + kk) << 13); };
    auto Bbase = [&](int buf, int kk) { return lds + 32768 + ((buf * 2 + kk) << 13); };

    auto stageA = [&](int buf, int kk, int kt) {
        const long kb = (long)kt * 64 + kk * 32 + co;
        _Float16* d = Abase(buf, kk) + (w << 9); // wave-uniform base: w*64 chunks
        gload16(A + (m0 + row0) * (long)lda + kb, d);
        gload16(A + (m0 + row0 + 128) * (long)lda + kb, d + 4096);
    };
    auto stageB = [&](int buf, int kk, int kt) {
        const long kb = (long)kt * 64 + kk * 32 + co;
        _Float16* d = Bbase(buf, kk) + (w << 9);
        gload16(B + (n0 + row0) * (long)ldb + kb, d);
        gload16(B + (n0 + row0 + 128) * (long)ldb + kb, d + 4096);
    };
    auto ldA = [&](int buf, int kk, int m) {
        return *(const half8*)(Abase(buf, kk) + (arow + m * 16) * 32 + fcol);
    };
    auto ldB = [&](int buf, int kk, int n) {
        return *(const half8*)(Bbase(buf, kk) + (brow + n * 16) * 32 + fcol);
    };

    floatx4 acc[8][4] = {};

#define MFMA16(MH)                                                                     \
    _Pragma("unroll") for (int mm = 0; mm < 4; ++mm)                                   \
    _Pragma("unroll") for (int nn = 0; nn < 4; ++nn)                                   \
        acc[(MH)*4 + mm][nn] =                                                         \
            __builtin_amdgcn_mfma_f32_16x16x32_f16(afr[mm], bfr[nn], acc[(MH)*4 + mm][nn], 0, 0, 0);

    // prologue: stage tile 0 in consumption order
    stageA(0, 0, 0); stageB(0, 0, 0); stageA(0, 1, 0); stageB(0, 1, 0);
    asm volatile("s_waitcnt vmcnt(4)" ::: "memory"); // tile0 kk0 landed (this wave)
    __builtin_amdgcn_s_barrier();                    // all waves

    for (int t = 0; t < nkt; ++t) {
        const int cur = t & 1, nxt = cur ^ 1;
        const bool pf = (t + 1 < nkt);
        const int kn = t + 1;
        half8 afr[4], bfr[4];
        // ---- phase 0: kk=0, mh=0 ----
#pragma unroll
        for (int nn = 0; nn < 4; ++nn) bfr[nn] = ldB(cur, 0, nn);
#pragma unroll
        for (int mm = 0; mm < 4; ++mm) afr[mm] = ldA(cur, 0, mm);
        if (pf) stageA(nxt, 0, kn);
        __builtin_amdgcn_s_barrier();
        asm volatile("s_waitcnt lgkmcnt(0)" ::: "memory");
        __builtin_amdgcn_sched_barrier(0);
        __builtin_amdgcn_s_setprio(1);
        MFMA16(0)
        __builtin_amdgcn_s_setprio(0);
        __builtin_amdgcn_s_barrier();
        // ---- phase 1: kk=0, mh=1 (reuse bfr) ----
#pragma unroll
        for (int mm = 0; mm < 4; ++mm) afr[mm] = ldA(cur, 0, mm + 4);
        if (pf) stageB(nxt, 0, kn);
        __builtin_amdgcn_s_barrier();
        asm volatile("s_waitcnt lgkmcnt(0)" ::: "memory");
        __builtin_amdgcn_sched_barrier(0);
        __builtin_amdgcn_s_setprio(1);
        MFMA16(1)
        __builtin_amdgcn_s_setprio(0);
        // cur kk1 ready: 4 younger stage-loads behind it if pf, else it's the tail
        if (pf) { asm volatile("s_waitcnt vmcnt(4)" ::: "memory"); }
        else    { asm volatile("s_waitcnt vmcnt(0)" ::: "memory"); }
        __builtin_amdgcn_s_barrier();
        // ---- phase 2: kk=1, mh=0 ----
#pragma unroll
        for (int nn = 0; nn < 4; ++nn) bfr[nn] = ldB(cur, 1, nn);
#pragma unroll
        for (int mm = 0; mm < 4; ++mm) afr[mm] = ldA(cur, 1, mm);
        if (pf) stageA(nxt, 1, kn);
        __builtin_amdgcn_s_barrier();
        asm volatile("s_waitcnt lgkmcnt(0)" ::: "memory");
        __builtin_amdgcn_sched_barrier(0);
        __builtin_amdgcn_s_setprio(1);
        MFMA16(0)
        __builtin_amdgcn_s_setprio(0);
        __builtin_amdgcn_s_barrier();
        // ---- phase 3: kk=1, mh=1 ----
#pragma unroll
        for (int mm = 0; mm < 4; ++mm) afr[mm] = ldA(cur, 1, mm + 4);
        if (pf) stageB(nxt, 1, kn);
        __builtin_amdgcn_s_barrier();
        asm volatile("s_waitcnt lgkmcnt(0)" ::: "memory");
        __builtin_amdgcn_sched_barrier(0);
        __builtin_amdgcn_s_setprio(1);
        MFMA16(1)
        __builtin_amdgcn_s_setprio(0);
        asm volatile("s_waitcnt vmcnt(4)" ::: "memory"); // next kk0 (staged ph0-1) ready
        __builtin_amdgcn_s_barrier();
    }
#undef MFMA16

    // epilogue: C/D layout col=lane&15, row=(lane>>4)*4+j
    const int r4 = (lane >> 4) * 4, ccol = lane & 15;
    if (MODE <= 1) {
        _Float16* C = (_Float16*)Cout + (long)b * sCb;
#pragma unroll
        for (int m = 0; m < 8; ++m) {
            const long rbase = m0 + wr * 128 + m * 16 + r4;
#pragma unroll
            for (int n = 0; n < 4; ++n) {
                const long cbase = n0 + wc * 64 + n * 16 + ccol;
#pragma unroll
                for (int j = 0; j < 4; ++j)
                    C[(rbase + j) * (long)ldc + cbase] = (_Float16)acc[m][n][j];
            }
        }
    } else {
        float* C = (float*)Cout + (long)b * sCb;
#pragma unroll
        for (int m = 0; m < 8; ++m) {
            const long rbase = m0 + wr * 128 + m * 16 + r4;
#pragma unroll
            for (int n = 0; n < 4; ++n) {
                const long cbase = n0 + wc * 64 + n * 16 + ccol;
#pragma unroll
                for (int j = 0; j < 4; ++j)
                    C[(rbase + j) * (long)ldc + cbase] = acc[m][n][j];
            }
        }
    }
}

// ---------------- causal row softmax, in-place f16 ----------------
__device__ __forceinline__ float blockReduce(float v, bool ismax, float* sb) {
#pragma unroll
    for (int o = 32; o; o >>= 1) {
        float t = __shfl_xor(v, o);
        v = ismax ? fmaxf(v, t) : v + t;
    }
    if ((threadIdx.x & 63) == 0) sb[threadIdx.x >> 6] = v;
    __syncthreads();
    v = ismax ? fmaxf(fmaxf(sb[0], sb[1]), fmaxf(sb[2], sb[3]))
              : (sb[0] + sb[1]) + (sb[2] + sb[3]);
    __syncthreads();
    return v;
}

__global__ __launch_bounds__(256) void softmax_rows_f16(_Float16* __restrict__ S, int T) {
    __shared__ float sb[4];
    const long row = blockIdx.x; // chunk-local b*T + t
    const int t = (int)(row % T);
    _Float16* s = S + row * (long)T;
    const int tid = threadIdx.x;
    const bool ld = (tid * 8 <= t);
    const int nstore = ((t >> 8) + 1) << 5; // cover the diagonal 256-tile for PV

    float v[8];
    float mx = -__builtin_inff();
    if (ld) {
        half8 hv = *(const half8*)(s + tid * 8);
#pragma unroll
        for (int j = 0; j < 8; ++j) {
            v[j] = (tid * 8 + j <= t) ? (float)hv[j] : -__builtin_inff();
            mx = fmaxf(mx, v[j]);
        }
    } else {
#pragma unroll
        for (int j = 0; j < 8; ++j) v[j] = -__builtin_inff();
    }
    const float m = blockReduce(mx, true, sb);

    float sum = 0.f;
#pragma unroll
    for (int j = 0; j < 8; ++j) {
        float p = __expf(v[j] - m); // exp(-inf)=0 masks
        v[j] = p;
        sum += p;
    }
    const float l = blockReduce(sum, false, sb);
    const float inv = 1.f / l;

    if (tid < nstore) {
        half8 o;
#pragma unroll
        for (int j = 0; j < 8; ++j) o[j] = (_Float16)(v[j] * inv);
        *(half8*)(s + tid * 8) = o;
    }
}

// ---------------- launch ----------------
extern "C" void kernel_launch(void* const* d_in, const int* in_sizes, int n_in,
                              void* d_out, int out_size, void* d_ws, size_t ws_size,
                              hipStream_t stream) {
    const float* x  = (const float*)d_in[0];
    const float* Wq = (const float*)d_in[1];
    const float* Wk = (const float*)d_in[2];
    const float* Wv = (const float*)d_in[3];
    float* out = (float*)d_out;

    const size_t XB = (size_t)TB * TT * TD; // 33.5M elems

    // d_out doubles as scratch: x16 lo half, K hi half (dead before PV overwrites).
    _Float16* x16 = (_Float16*)d_out;
    _Float16* Kh  = (_Float16*)d_out + XB;

    char* ws = (char*)d_ws;
    size_t off = 0;
    auto carve = [&](size_t bytes) { char* p = ws + off; off = (off + bytes + 255) & ~(size_t)255; return p; };
    _Float16* wqt = (_Float16*)carve((size_t)TD * TD * 2);
    _Float16* wkt = (_Float16*)carve((size_t)TD * TD * 2);
    _Float16* wvt = (_Float16*)carve((size_t)TD * TD * 2);
    _Float16* Qh  = (_Float16*)carve(XB * 2);   // [B*T][1024]
    _Float16* Vt  = (_Float16*)carve(XB * 2);   // [B][1024][2048]

    const size_t CH = (size_t)TT * TT * 2;      // 8.39 MB / batch
    int NB = 16;
    while (NB > 1 && off + (size_t)NB * CH > ws_size) NB >>= 1;
    _Float16* Sc = (_Float16*)carve((size_t)NB * CH);

    // 1. x -> f16
    cvt_f32_f16<<<2048, 256, 0, stream>>>(x, x16, (long)XB);
    // 2. W^T f16
    transpose_cvt_w<<<dim3(32, 32), dim3(32, 8), 0, stream>>>(Wq, wqt);
    transpose_cvt_w<<<dim3(32, 32), dim3(32, 8), 0, stream>>>(Wk, wkt);
    transpose_cvt_w<<<dim3(32, 32), dim3(32, 8), 0, stream>>>(Wv, wvt);

    // 3. Q = x @ Wq : M=32768, N=1024, K=1024 (128x4 tiles)
    gemm256<0><<<dim3(128 * 4, 1), 512, 0, stream>>>(x16, wqt, Qh, TD, TD, TD, TD,
                                                     0, 0, 0, 4, 128);
    // 4. K = x @ Wk -> d_out hi
    gemm256<0><<<dim3(128 * 4, 1), 512, 0, stream>>>(x16, wkt, Kh, TD, TD, TD, TD,
                                                     0, 0, 0, 4, 128);
    // 5. Vt[b] = (x[b] @ Wv)^T : M=1024 (4), N=2048 (8)
    gemm256<0><<<dim3(4 * 8, TB), 512, 0, stream>>>(wvt, x16, Vt, TD, TD, TD, TT,
                                                    0, (long)TT * TD, (long)TD * TT, 8, 4);

    // 6. per chunk of NB batches
    for (int cb = 0; cb < TB; cb += NB) {
        // S = Q K^T, lower-tri 256-tiles (36/batch), f16
        gemm256<1><<<dim3(36, NB), 512, 0, stream>>>(Qh + (size_t)cb * TT * TD,
                                                     Kh + (size_t)cb * TT * TD, Sc,
                                                     TD, TD, TD, TT,
                                                     (long)TT * TD, (long)TT * TD, (long)TT * TT, 8, 8);
        // causal softmax, in-place
        softmax_rows_f16<<<NB * TT, 256, 0, stream>>>(Sc, TT);
        // O = P @ V^T : M-tiles 8 (reversed), N-tiles 4, K trimmed causally
        gemm256<2><<<dim3(8 * 4, NB), 512, 0, stream>>>(Sc, Vt + (size_t)cb * TD * TT,
                                                        out + (size_t)cb * TT * TD, TT,
                                                        TT, TT, TD,
                                                        (long)TT * TT, (long)TD * TT, (long)TT * TD, 4, 8);
    }
}

// Round 5
// 483.517 us; speedup vs baseline: 1.5029x; 1.1243x over previous
//
#include <hip/hip_runtime.h>
#include <hip/hip_bf16.h>

// Single-head causal attention, B=16, T=2048, D=H=1024.
// cvt x->f16 (d_out lo) | transpose W | fused QK GEMM (Q->ws, K->d_out hi) |
// Vt GEMM (ws) | per-chunk: S=QK^T (tri,f16) -> causal softmax (wave/row) ->
// O = P@V^T (LPT-ordered) -> d_out f32.
// GEMM: 256x256 tile, BK=64, 8 waves, 4-phase/K-tile, counted vmcnt (last-iter
// drains 0), swizzled k-major LDS, global_load_lds x16B, XCD-bijective swizzle.
// r5: PV grid flattened + LPT (heavy ti first) to fix 2x load-imbalance tail;
//     Q+K fused into one GEMM (saves one 67MB x16 pass); softmax wave-per-row.

typedef _Float16 half8 __attribute__((ext_vector_type(8)));
typedef _Float16 half4v __attribute__((ext_vector_type(4)));
typedef float floatx4 __attribute__((ext_vector_type(4)));

#define TB 16
#define TT 2048
#define TD 1024

// ---------------- convert x fp32 -> fp16 ----------------
__global__ void cvt_f32_f16(const float* __restrict__ in, _Float16* __restrict__ out, long n) {
    long i = ((long)blockIdx.x * blockDim.x + threadIdx.x) * 4;
    long stride = (long)gridDim.x * blockDim.x * 4;
    for (; i < n; i += stride) {
        float4 f = *(const float4*)(in + i);
        half4v h;
        h[0] = (_Float16)f.x; h[1] = (_Float16)f.y;
        h[2] = (_Float16)f.z; h[3] = (_Float16)f.w;
        *(half4v*)(out + i) = h;
    }
}

// ---------------- transpose + convert W [1024,1024] ----------------
__global__ void transpose_cvt_w(const float* __restrict__ in, _Float16* __restrict__ out) {
    __shared__ float tile[32][33];
    const int bx = blockIdx.x * 32, by = blockIdx.y * 32;
    const int tx = threadIdx.x, ty = threadIdx.y; // block 32x8
#pragma unroll
    for (int i = ty; i < 32; i += 8) tile[i][tx] = in[(long)(by + i) * 1024 + bx + tx];
    __syncthreads();
#pragma unroll
    for (int i = ty; i < 32; i += 8) out[(long)(bx + i) * 1024 + by + tx] = (_Float16)tile[tx][i];
}

// ---------------- 256x256 8-wave 4-phase BT GEMM ----------------
// C[i,j] = sum_k A[i,k]*B[j,k]; A:[M,K] f16 (lda), B:[N,K] f16 (ldb)
// MODE 0: f16 out, plain grid.     MODE 1: f16 out, lower-tri tile grid.
// MODE 2: f32 out, 1D LPT grid (heavy ti first), K trimmed to (ti+1)*256.
// MODE 3: f16 out, plain grid, split outputs at col TD (Cout / Cout2).
__device__ __forceinline__ void gload16(const _Float16* g, _Float16* l) {
    __builtin_amdgcn_global_load_lds((const __attribute__((address_space(1))) void*)g,
                                     (__attribute__((address_space(3))) void*)l, 16, 0, 0);
}

template <int MODE>
__global__ __launch_bounds__(512, 2) void gemm256(const _Float16* __restrict__ A,
                                                  const _Float16* __restrict__ B,
                                                  void* __restrict__ Cout,
                                                  void* __restrict__ Cout2,
                                                  int K, int lda, int ldb, int ldc,
                                                  long sAb, long sBb, long sCb,
                                                  int tilesN, int tilesM, int nb) {
    // LDS: As regions [2buf][2kk][256][32] f16 (64KB) then Bs same (64KB).
    __shared__ _Float16 lds[65536];
    const int tid = threadIdx.x, lane = tid & 63, w = tid >> 6;
    const int wr = w >> 2, wc = w & 3;

    int b, ti, tj;
    if (MODE == 2) {
        // LPT: raw order descending work; XCD swizzle within equal-work group
        const int grp = nb * 4;
        const int g = blockIdx.x / grp;
        ti = tilesM - 1 - g;
        int i2 = blockIdx.x - g * grp;
        const int q = grp >> 3, r = grp & 7, xcd = i2 & 7, idx = i2 >> 3;
        i2 = (xcd < r ? xcd * (q + 1) : r * (q + 1) + (xcd - r) * q) + idx;
        b = i2 >> 2; tj = i2 & 3;
    } else {
        int bx = blockIdx.x;
        const int nwg = gridDim.x, q = nwg >> 3, r = nwg & 7, xcd = bx & 7, idx = bx >> 3;
        bx = (xcd < r ? xcd * (q + 1) : r * (q + 1) + (xcd - r) * q) + idx;
        b = blockIdx.y;
        if (MODE == 1) {
            int rd = bx; ti = 0;
            while (rd > ti) { rd -= ti + 1; ++ti; }
            tj = rd;
        } else {
            ti = bx / tilesN; tj = bx % tilesN;
        }
    }
    A += (long)b * sAb;
    B += (long)b * sBb;
    const long m0 = (long)ti * 256, n0 = (long)tj * 256;
    const int nkt = (MODE == 2) ? (ti + 1) * 4 : (K >> 6);

    // staging: thread stages chunk q0=tid and q0+512 per (matrix, region).
    const int row0 = tid >> 2;                                  // 0..127 (+128 for 2nd load)
    const int co   = (((tid & 3) ^ ((tid >> 3) & 3)) << 3);     // inverse-swizzled f16 col
    // frag read: lane wants logical chunk (lane>>4); stored at chunk ^ ((row>>1)&3)
    const int fcol = ((((lane >> 4) ^ (lane >> 1)) & 3) << 3);
    const int arow = wr * 128 + (lane & 15);
    const int brow = wc * 64 + (lane & 15);

    auto Abase = [&](int buf, int kk) { return lds + ((buf * 2 + kk) << 13); };
    auto Bbase = [&](int buf, int kk) { return lds + 32768 + ((buf * 2 + kk) << 13); };

    auto stageA = [&](int buf, int kk, int kt) {
        const long kb = (long)kt * 64 + kk * 32 + co;
        _Float16* d = Abase(buf, kk) + (w << 9); // wave-uniform base: w*64 chunks
        gload16(A + (m0 + row0) * (long)lda + kb, d);
        gload16(A + (m0 + row0 + 128) * (long)lda + kb, d + 4096);
    };
    auto stageB = [&](int buf, int kk, int kt) {
        const long kb = (long)kt * 64 + kk * 32 + co;
        _Float16* d = Bbase(buf, kk) + (w << 9);
        gload16(B + (n0 + row0) * (long)ldb + kb, d);
        gload16(B + (n0 + row0 + 128) * (long)ldb + kb, d + 4096);
    };
    auto ldA = [&](int buf, int kk, int m) {
        return *(const half8*)(Abase(buf, kk) + (arow + m * 16) * 32 + fcol);
    };
    auto ldB = [&](int buf, int kk, int n) {
        return *(const half8*)(Bbase(buf, kk) + (brow + n * 16) * 32 + fcol);
    };

    floatx4 acc[8][4] = {};

#define MFMA16(MH)                                                                     \
    _Pragma("unroll") for (int mm = 0; mm < 4; ++mm)                                   \
    _Pragma("unroll") for (int nn = 0; nn < 4; ++nn)                                   \
        acc[(MH)*4 + mm][nn] =                                                         \
            __builtin_amdgcn_mfma_f32_16x16x32_f16(afr[mm], bfr[nn], acc[(MH)*4 + mm][nn], 0, 0, 0);

    // prologue: stage tile 0 in consumption order
    stageA(0, 0, 0); stageB(0, 0, 0); stageA(0, 1, 0); stageB(0, 1, 0);
    asm volatile("s_waitcnt vmcnt(4)" ::: "memory"); // tile0 kk0 landed (this wave)
    __builtin_amdgcn_s_barrier();                    // all waves

    for (int t = 0; t < nkt; ++t) {
        const int cur = t & 1, nxt = cur ^ 1;
        const bool pf = (t + 1 < nkt);
        const int kn = t + 1;
        half8 afr[4], bfr[4];
        // ---- phase 0: kk=0, mh=0 ----
#pragma unroll
        for (int nn = 0; nn < 4; ++nn) bfr[nn] = ldB(cur, 0, nn);
#pragma unroll
        for (int mm = 0; mm < 4; ++mm) afr[mm] = ldA(cur, 0, mm);
        if (pf) stageA(nxt, 0, kn);
        __builtin_amdgcn_s_barrier();
        asm volatile("s_waitcnt lgkmcnt(0)" ::: "memory");
        __builtin_amdgcn_sched_barrier(0);
        __builtin_amdgcn_s_setprio(1);
        MFMA16(0)
        __builtin_amdgcn_s_setprio(0);
        __builtin_amdgcn_s_barrier();
        // ---- phase 1: kk=0, mh=1 (reuse bfr) ----
#pragma unroll
        for (int mm = 0; mm < 4; ++mm) afr[mm] = ldA(cur, 0, mm + 4);
        if (pf) stageB(nxt, 0, kn);
        __builtin_amdgcn_s_barrier();
        asm volatile("s_waitcnt lgkmcnt(0)" ::: "memory");
        __builtin_amdgcn_sched_barrier(0);
        __builtin_amdgcn_s_setprio(1);
        MFMA16(1)
        __builtin_amdgcn_s_setprio(0);
        // cur kk1 ready: 4 younger stage-loads behind it if pf, else it's the tail
        if (pf) { asm volatile("s_waitcnt vmcnt(4)" ::: "memory"); }
        else    { asm volatile("s_waitcnt vmcnt(0)" ::: "memory"); }
        __builtin_amdgcn_s_barrier();
        // ---- phase 2: kk=1, mh=0 ----
#pragma unroll
        for (int nn = 0; nn < 4; ++nn) bfr[nn] = ldB(cur, 1, nn);
#pragma unroll
        for (int mm = 0; mm < 4; ++mm) afr[mm] = ldA(cur, 1, mm);
        if (pf) stageA(nxt, 1, kn);
        __builtin_amdgcn_s_barrier();
        asm volatile("s_waitcnt lgkmcnt(0)" ::: "memory");
        __builtin_amdgcn_sched_barrier(0);
        __builtin_amdgcn_s_setprio(1);
        MFMA16(0)
        __builtin_amdgcn_s_setprio(0);
        __builtin_amdgcn_s_barrier();
        // ---- phase 3: kk=1, mh=1 ----
#pragma unroll
        for (int mm = 0; mm < 4; ++mm) afr[mm] = ldA(cur, 1, mm + 4);
        if (pf) stageB(nxt, 1, kn);
        __builtin_amdgcn_s_barrier();
        asm volatile("s_waitcnt lgkmcnt(0)" ::: "memory");
        __builtin_amdgcn_sched_barrier(0);
        __builtin_amdgcn_s_setprio(1);
        MFMA16(1)
        __builtin_amdgcn_s_setprio(0);
        asm volatile("s_waitcnt vmcnt(4)" ::: "memory"); // next kk0 (staged ph0-1) ready
        __builtin_amdgcn_s_barrier();
    }
#undef MFMA16

    // epilogue: C/D layout col=lane&15, row=(lane>>4)*4+j
    const int r4 = (lane >> 4) * 4, ccol = lane & 15;
    if (MODE != 2) {
        _Float16* C;
        long nb0 = n0;
        if (MODE == 3 && n0 >= TD) { C = (_Float16*)Cout2; nb0 = n0 - TD; }
        else                        C = (_Float16*)Cout + (long)b * sCb;
#pragma unroll
        for (int m = 0; m < 8; ++m) {
            const long rbase = m0 + wr * 128 + m * 16 + r4;
#pragma unroll
            for (int n = 0; n < 4; ++n) {
                const long cbase = nb0 + wc * 64 + n * 16 + ccol;
#pragma unroll
                for (int j = 0; j < 4; ++j)
                    C[(rbase + j) * (long)ldc + cbase] = (_Float16)acc[m][n][j];
            }
        }
    } else {
        float* C = (float*)Cout + (long)b * sCb;
#pragma unroll
        for (int m = 0; m < 8; ++m) {
            const long rbase = m0 + wr * 128 + m * 16 + r4;
#pragma unroll
            for (int n = 0; n < 4; ++n) {
                const long cbase = n0 + wc * 64 + n * 16 + ccol;
#pragma unroll
                for (int j = 0; j < 4; ++j)
                    C[(rbase + j) * (long)ldc + cbase] = acc[m][n][j];
            }
        }
    }
}

// ---------------- causal row softmax, wave-per-row, in-place f16 ----------------
__global__ __launch_bounds__(256) void softmax_rows_f16(_Float16* __restrict__ S, int T) {
    const int wv = threadIdx.x >> 6, lane = threadIdx.x & 63;
    const long row = (long)blockIdx.x * 4 + wv; // chunk-local b*T + t
    const int t = (int)(row & (T - 1));
    _Float16* s = S + row * (long)T;
    const int nstore = ((t >> 8) + 1) << 8; // cover the diagonal 256-tile for PV

    float v[4][8];
    float mx = -__builtin_inff();
#pragma unroll
    for (int c = 0; c < 4; ++c) {
        const int col0 = (c * 64 + lane) * 8;
        if (col0 <= t) {
            half8 hv = *(const half8*)(s + col0);
#pragma unroll
            for (int j = 0; j < 8; ++j) {
                v[c][j] = (col0 + j <= t) ? (float)hv[j] : -__builtin_inff();
                mx = fmaxf(mx, v[c][j]);
            }
        } else {
#pragma unroll
            for (int j = 0; j < 8; ++j) v[c][j] = -__builtin_inff();
        }
    }
#pragma unroll
    for (int o = 32; o; o >>= 1) mx = fmaxf(mx, __shfl_xor(mx, o));

    float sum = 0.f;
#pragma unroll
    for (int c = 0; c < 4; ++c)
#pragma unroll
        for (int j = 0; j < 8; ++j) {
            float p = __expf(v[c][j] - mx); // exp(-inf)=0 masks
            v[c][j] = p;
            sum += p;
        }
#pragma unroll
    for (int o = 32; o; o >>= 1) sum += __shfl_xor(sum, o);
    const float inv = 1.f / sum;

#pragma unroll
    for (int c = 0; c < 4; ++c) {
        const int col0 = (c * 64 + lane) * 8;
        if (col0 < nstore) {
            half8 o;
#pragma unroll
            for (int j = 0; j < 8; ++j) o[j] = (_Float16)(v[c][j] * inv);
            *(half8*)(s + col0) = o;
        }
    }
}

// ---------------- launch ----------------
extern "C" void kernel_launch(void* const* d_in, const int* in_sizes, int n_in,
                              void* d_out, int out_size, void* d_ws, size_t ws_size,
                              hipStream_t stream) {
    const float* x  = (const float*)d_in[0];
    const float* Wq = (const float*)d_in[1];
    const float* Wk = (const float*)d_in[2];
    const float* Wv = (const float*)d_in[3];
    float* out = (float*)d_out;

    const size_t XB = (size_t)TB * TT * TD; // 33.5M elems

    // d_out doubles as scratch: x16 lo half, K hi half (dead before PV overwrites).
    _Float16* x16 = (_Float16*)d_out;
    _Float16* Kh  = (_Float16*)d_out + XB;

    char* ws = (char*)d_ws;
    size_t off = 0;
    auto carve = [&](size_t bytes) { char* p = ws + off; off = (off + bytes + 255) & ~(size_t)255; return p; };
    _Float16* wqt = (_Float16*)carve((size_t)TD * TD * 2); // wqt & wkt contiguous:
    _Float16* wkt = (_Float16*)carve((size_t)TD * TD * 2); //   [Wq^T ; Wk^T] = B [2048,1024]
    _Float16* wvt = (_Float16*)carve((size_t)TD * TD * 2);
    _Float16* Qh  = (_Float16*)carve(XB * 2);   // [B*T][1024]
    _Float16* Vt  = (_Float16*)carve(XB * 2);   // [B][1024][2048]

    const size_t CH = (size_t)TT * TT * 2;      // 8.39 MB / batch
    int NB = 16;
    while (NB > 1 && off + (size_t)NB * CH > ws_size) NB >>= 1;
    _Float16* Sc = (_Float16*)carve((size_t)NB * CH);

    // 1. x -> f16
    cvt_f32_f16<<<2048, 256, 0, stream>>>(x, x16, (long)XB);
    // 2. W^T f16
    transpose_cvt_w<<<dim3(32, 32), dim3(32, 8), 0, stream>>>(Wq, wqt);
    transpose_cvt_w<<<dim3(32, 32), dim3(32, 8), 0, stream>>>(Wk, wkt);
    transpose_cvt_w<<<dim3(32, 32), dim3(32, 8), 0, stream>>>(Wv, wvt);

    // 3. fused [Q|K] = x @ [Wq|Wk] : M=32768 (128 tiles), N=2048 (8 tiles);
    //    epilogue routes cols <1024 -> Qh, >=1024 -> Kh (d_out hi).
    gemm256<3><<<dim3(128 * 8, 1), 512, 0, stream>>>(x16, wqt, Qh, Kh, TD, TD, TD, TD,
                                                     0, 0, 0, 8, 128, 0);
    // 4. Vt[b] = (x[b] @ Wv)^T : M=1024 (4), N=2048 (8)
    gemm256<0><<<dim3(4 * 8, TB), 512, 0, stream>>>(wvt, x16, Vt, nullptr, TD, TD, TD, TT,
                                                    0, (long)TT * TD, (long)TD * TT, 8, 4, 0);

    // 5. per chunk of NB batches
    for (int cb = 0; cb < TB; cb += NB) {
        // S = Q K^T, lower-tri 256-tiles (36/batch), f16
        gemm256<1><<<dim3(36, NB), 512, 0, stream>>>(Qh + (size_t)cb * TT * TD,
                                                     Kh + (size_t)cb * TT * TD, Sc, nullptr,
                                                     TD, TD, TD, TT,
                                                     (long)TT * TD, (long)TT * TD, (long)TT * TT, 8, 8, 0);
        // causal softmax, in-place, wave-per-row (4 rows/block)
        softmax_rows_f16<<<NB * TT / 4, 256, 0, stream>>>(Sc, TT);
        // O = P @ V^T : 1D LPT grid (heavy ti first), K trimmed causally
        gemm256<2><<<dim3(NB * 32, 1), 512, 0, stream>>>(Sc, Vt + (size_t)cb * TD * TT,
                                                         out + (size_t)cb * TT * TD, nullptr, TT,
                                                         TT, TT, TD,
                                                         (long)TT * TT, (long)TD * TT, (long)TT * TD, 4, 8, NB);
    }
}

// Round 6
// 472.425 us; speedup vs baseline: 1.5382x; 1.0235x over previous
//
#include <hip/hip_runtime.h>
#include <hip/hip_bf16.h>

// Single-head causal attention, B=16, T=2048, D=H=1024.
// cvt x->f16 (d_out lo) | transpose W | fused QK GEMM (Q->ws, K->d_out hi) |
// Vt GEMM (ws) | per-chunk: S=QK^T (tri,f16) -> causal softmax (wave/row) ->
// O = P@V^T (LPT-ordered) -> d_out f32.
// GEMM r6: software-pipelined 4-phase loop. Per phase: MFMA issued first,
// then NEXT phase's ds_reads (ping-pong reg sets afE/afO,bfE/bfO) overlap the
// matrix pipe, then 1 half-tile stage. 1 barrier/phase. Stage-ahead 1.5
// K-tiles, vmcnt(6) publish at P0/P2 ends only. Clamped tail staging keeps
// the vmcnt ledger uniform; vmcnt(0) before epilogue.

typedef _Float16 half8 __attribute__((ext_vector_type(8)));
typedef _Float16 half4v __attribute__((ext_vector_type(4)));
typedef float floatx4 __attribute__((ext_vector_type(4)));

#define TB 16
#define TT 2048
#define TD 1024

// ---------------- convert x fp32 -> fp16 ----------------
__global__ void cvt_f32_f16(const float* __restrict__ in, _Float16* __restrict__ out, long n) {
    long i = ((long)blockIdx.x * blockDim.x + threadIdx.x) * 4;
    long stride = (long)gridDim.x * blockDim.x * 4;
    for (; i < n; i += stride) {
        float4 f = *(const float4*)(in + i);
        half4v h;
        h[0] = (_Float16)f.x; h[1] = (_Float16)f.y;
        h[2] = (_Float16)f.z; h[3] = (_Float16)f.w;
        *(half4v*)(out + i) = h;
    }
}

// ---------------- transpose + convert W [1024,1024] ----------------
__global__ void transpose_cvt_w(const float* __restrict__ in, _Float16* __restrict__ out) {
    __shared__ float tile[32][33];
    const int bx = blockIdx.x * 32, by = blockIdx.y * 32;
    const int tx = threadIdx.x, ty = threadIdx.y; // block 32x8
#pragma unroll
    for (int i = ty; i < 32; i += 8) tile[i][tx] = in[(long)(by + i) * 1024 + bx + tx];
    __syncthreads();
#pragma unroll
    for (int i = ty; i < 32; i += 8) out[(long)(bx + i) * 1024 + by + tx] = (_Float16)tile[tx][i];
}

// ---------------- 256x256 8-wave pipelined BT GEMM ----------------
// C[i,j] = sum_k A[i,k]*B[j,k]; A:[M,K] f16 (lda), B:[N,K] f16 (ldb)
// MODE 0: f16 out, plain grid.     MODE 1: f16 out, lower-tri tile grid.
// MODE 2: f32 out, 1D LPT grid (heavy ti first), K trimmed to (ti+1)*256.
// MODE 3: f16 out, plain grid, split outputs at col TD (Cout / Cout2).
__device__ __forceinline__ void gload16(const _Float16* g, _Float16* l) {
    __builtin_amdgcn_global_load_lds((const __attribute__((address_space(1))) void*)g,
                                     (__attribute__((address_space(3))) void*)l, 16, 0, 0);
}

template <int MODE>
__global__ __launch_bounds__(512, 2) void gemm256(const _Float16* __restrict__ A,
                                                  const _Float16* __restrict__ B,
                                                  void* __restrict__ Cout,
                                                  void* __restrict__ Cout2,
                                                  int K, int lda, int ldb, int ldc,
                                                  long sAb, long sBb, long sCb,
                                                  int tilesN, int tilesM, int nb) {
    // LDS: As regions [2buf][2kk][256][32] f16 (64KB) then Bs same (64KB).
    __shared__ _Float16 lds[65536];
    const int tid = threadIdx.x, lane = tid & 63, w = tid >> 6;
    const int wr = w >> 2, wc = w & 3;

    int b, ti, tj;
    if (MODE == 2) {
        // LPT: raw order descending work; XCD swizzle within equal-work group
        const int grp = nb * 4;
        const int g = blockIdx.x / grp;
        ti = tilesM - 1 - g;
        int i2 = blockIdx.x - g * grp;
        const int q = grp >> 3, r = grp & 7, xcd = i2 & 7, idx = i2 >> 3;
        i2 = (xcd < r ? xcd * (q + 1) : r * (q + 1) + (xcd - r) * q) + idx;
        b = i2 >> 2; tj = i2 & 3;
    } else {
        int bx = blockIdx.x;
        const int nwg = gridDim.x, q = nwg >> 3, r = nwg & 7, xcd = bx & 7, idx = bx >> 3;
        bx = (xcd < r ? xcd * (q + 1) : r * (q + 1) + (xcd - r) * q) + idx;
        b = blockIdx.y;
        if (MODE == 1) {
            int rd = bx; ti = 0;
            while (rd > ti) { rd -= ti + 1; ++ti; }
            tj = rd;
        } else {
            ti = bx / tilesN; tj = bx % tilesN;
        }
    }
    A += (long)b * sAb;
    B += (long)b * sBb;
    const long m0 = (long)ti * 256, n0 = (long)tj * 256;
    const int nkt = (MODE == 2) ? (ti + 1) * 4 : (K >> 6);

    // staging: thread stages chunk q0=tid and q0+512 per (matrix, region).
    const int row0 = tid >> 2;                                  // 0..127 (+128 for 2nd load)
    const int co   = (((tid & 3) ^ ((tid >> 3) & 3)) << 3);     // inverse-swizzled f16 col
    // frag read: lane wants logical chunk (lane>>4); stored at chunk ^ ((row>>1)&3)
    const int fcol = ((((lane >> 4) ^ (lane >> 1)) & 3) << 3);
    const int arow = wr * 128 + (lane & 15);
    const int brow = wc * 64 + (lane & 15);

    auto Abase = [&](int buf, int kk) { return lds + ((buf * 2 + kk) << 13); };
    auto Bbase = [&](int buf, int kk) { return lds + 32768 + ((buf * 2 + kk) << 13); };

    auto stageA = [&](int buf, int kk, int kt) {
        const long kb = (long)kt * 64 + kk * 32 + co;
        _Float16* d = Abase(buf, kk) + (w << 9); // wave-uniform base: w*64 chunks
        gload16(A + (m0 + row0) * (long)lda + kb, d);
        gload16(A + (m0 + row0 + 128) * (long)lda + kb, d + 4096);
    };
    auto stageB = [&](int buf, int kk, int kt) {
        const long kb = (long)kt * 64 + kk * 32 + co;
        _Float16* d = Bbase(buf, kk) + (w << 9);
        gload16(B + (n0 + row0) * (long)ldb + kb, d);
        gload16(B + (n0 + row0 + 128) * (long)ldb + kb, d + 4096);
    };
    auto ldA = [&](int buf, int kk, int m) {
        return *(const half8*)(Abase(buf, kk) + (arow + m * 16) * 32 + fcol);
    };
    auto ldB = [&](int buf, int kk, int n) {
        return *(const half8*)(Bbase(buf, kk) + (brow + n * 16) * 32 + fcol);
    };

    floatx4 acc[8][4] = {};
    half8 afE[4], afO[4], bfE[4], bfO[4];

#define MFMA_Q(MH, BF, AF)                                                             \
    _Pragma("unroll") for (int mm = 0; mm < 4; ++mm)                                   \
    _Pragma("unroll") for (int nn = 0; nn < 4; ++nn)                                   \
        acc[(MH)*4 + mm][nn] =                                                         \
            __builtin_amdgcn_mfma_f32_16x16x32_f16(AF[mm], BF[nn], acc[(MH)*4 + mm][nn], 0, 0, 0);

    // prologue: stage H(0,0) H(0,1) H(1,0) = 12 loads, 1.5 K-tiles ahead
    {
        const int k1 = (1 < nkt) ? 1 : nkt - 1;
        stageA(0, 0, 0); stageB(0, 0, 0);
        stageA(0, 1, 0); stageB(0, 1, 0);
        stageA(1, 0, k1); stageB(1, 0, k1);
    }
    asm volatile("s_waitcnt vmcnt(8)" ::: "memory"); // H(0,0) landed (this wave)
    __builtin_amdgcn_s_barrier();                    // publish H(0,0)
#pragma unroll
    for (int nn = 0; nn < 4; ++nn) bfE[nn] = ldB(0, 0, nn);
#pragma unroll
    for (int mm = 0; mm < 4; ++mm) afE[mm] = ldA(0, 0, mm);

    for (int t = 0; t < nkt; ++t) {
        const int cur = t & 1, nxt = cur ^ 1;
        const int kt1 = (t + 1 < nkt) ? t + 1 : nkt - 1;
        const int kt2 = (t + 2 < nkt) ? t + 2 : nkt - 1;
        // ---- P0: MFMA q0(cur,kk0) ; reads afO<-A(cur,0,hi) ; stage A(t+1,1) ----
        asm volatile("s_waitcnt lgkmcnt(0)" ::: "memory");
        __builtin_amdgcn_sched_barrier(0);
        __builtin_amdgcn_s_setprio(1);
        MFMA_Q(0, bfE, afE)
        __builtin_amdgcn_s_setprio(0);
#pragma unroll
        for (int mm = 0; mm < 4; ++mm) afO[mm] = ldA(cur, 0, mm + 4);
        stageA(nxt, 1, kt1);
        asm volatile("s_waitcnt vmcnt(6)" ::: "memory"); // H(t,1) landed
        __builtin_amdgcn_s_barrier();                    // publish H(t,1)
        // ---- P1: MFMA q1(cur,kk0) ; reads bfO,afE<-(cur,1) ; stage B(t+1,1) ----
        asm volatile("s_waitcnt lgkmcnt(0)" ::: "memory");
        __builtin_amdgcn_sched_barrier(0);
        __builtin_amdgcn_s_setprio(1);
        MFMA_Q(1, bfE, afO)
        __builtin_amdgcn_s_setprio(0);
#pragma unroll
        for (int nn = 0; nn < 4; ++nn) bfO[nn] = ldB(cur, 1, nn);
#pragma unroll
        for (int mm = 0; mm < 4; ++mm) afE[mm] = ldA(cur, 1, mm);
        stageB(nxt, 1, kt1);
        __builtin_amdgcn_s_barrier();
        // ---- P2: MFMA q0(cur,kk1) ; reads afO<-A(cur,1,hi) ; stage A(t+2,0) ----
        asm volatile("s_waitcnt lgkmcnt(0)" ::: "memory");
        __builtin_amdgcn_sched_barrier(0);
        __builtin_amdgcn_s_setprio(1);
        MFMA_Q(0, bfO, afE)
        __builtin_amdgcn_s_setprio(0);
#pragma unroll
        for (int mm = 0; mm < 4; ++mm) afO[mm] = ldA(cur, 1, mm + 4);
        stageA(cur, 0, kt2); // (t+2)&1 == t&1
        asm volatile("s_waitcnt vmcnt(6)" ::: "memory"); // H(t+1,0) landed
        __builtin_amdgcn_s_barrier();                    // publish H(t+1,0)
        // ---- P3: MFMA q1(cur,kk1) ; reads bfE,afE<-(nxt,0) ; stage B(t+2,0) ----
        asm volatile("s_waitcnt lgkmcnt(0)" ::: "memory");
        __builtin_amdgcn_sched_barrier(0);
        __builtin_amdgcn_s_setprio(1);
        MFMA_Q(1, bfO, afO)
        __builtin_amdgcn_s_setprio(0);
#pragma unroll
        for (int nn = 0; nn < 4; ++nn) bfE[nn] = ldB(nxt, 0, nn);
#pragma unroll
        for (int mm = 0; mm < 4; ++mm) afE[mm] = ldA(nxt, 0, mm);
        stageB(cur, 0, kt2);
        __builtin_amdgcn_s_barrier();
    }
#undef MFMA_Q
    asm volatile("s_waitcnt vmcnt(0) lgkmcnt(0)" ::: "memory"); // drain DMA before exit

    // epilogue: C/D layout col=lane&15, row=(lane>>4)*4+j
    const int r4 = (lane >> 4) * 4, ccol = lane & 15;
    if (MODE != 2) {
        _Float16* C;
        long nb0 = n0;
        if (MODE == 3 && n0 >= TD) { C = (_Float16*)Cout2; nb0 = n0 - TD; }
        else                        C = (_Float16*)Cout + (long)b * sCb;
#pragma unroll
        for (int m = 0; m < 8; ++m) {
            const long rbase = m0 + wr * 128 + m * 16 + r4;
#pragma unroll
            for (int n = 0; n < 4; ++n) {
                const long cbase = nb0 + wc * 64 + n * 16 + ccol;
#pragma unroll
                for (int j = 0; j < 4; ++j)
                    C[(rbase + j) * (long)ldc + cbase] = (_Float16)acc[m][n][j];
            }
        }
    } else {
        float* C = (float*)Cout + (long)b * sCb;
#pragma unroll
        for (int m = 0; m < 8; ++m) {
            const long rbase = m0 + wr * 128 + m * 16 + r4;
#pragma unroll
            for (int n = 0; n < 4; ++n) {
                const long cbase = n0 + wc * 64 + n * 16 + ccol;
#pragma unroll
                for (int j = 0; j < 4; ++j)
                    C[(rbase + j) * (long)ldc + cbase] = acc[m][n][j];
            }
        }
    }
}

// ---------------- causal row softmax, wave-per-row, in-place f16 ----------------
__global__ __launch_bounds__(256) void softmax_rows_f16(_Float16* __restrict__ S, int T) {
    const int wv = threadIdx.x >> 6, lane = threadIdx.x & 63;
    const long row = (long)blockIdx.x * 4 + wv; // chunk-local b*T + t
    const int t = (int)(row & (T - 1));
    _Float16* s = S + row * (long)T;
    const int nstore = ((t >> 8) + 1) << 8; // cover the diagonal 256-tile for PV

    float v[4][8];
    float mx = -__builtin_inff();
#pragma unroll
    for (int c = 0; c < 4; ++c) {
        const int col0 = (c * 64 + lane) * 8;
        if (col0 <= t) {
            half8 hv = *(const half8*)(s + col0);
#pragma unroll
            for (int j = 0; j < 8; ++j) {
                v[c][j] = (col0 + j <= t) ? (float)hv[j] : -__builtin_inff();
                mx = fmaxf(mx, v[c][j]);
            }
        } else {
#pragma unroll
            for (int j = 0; j < 8; ++j) v[c][j] = -__builtin_inff();
        }
    }
#pragma unroll
    for (int o = 32; o; o >>= 1) mx = fmaxf(mx, __shfl_xor(mx, o));

    float sum = 0.f;
#pragma unroll
    for (int c = 0; c < 4; ++c)
#pragma unroll
        for (int j = 0; j < 8; ++j) {
            float p = __expf(v[c][j] - mx); // exp(-inf)=0 masks
            v[c][j] = p;
            sum += p;
        }
#pragma unroll
    for (int o = 32; o; o >>= 1) sum += __shfl_xor(sum, o);
    const float inv = 1.f / sum;

#pragma unroll
    for (int c = 0; c < 4; ++c) {
        const int col0 = (c * 64 + lane) * 8;
        if (col0 < nstore) {
            half8 o;
#pragma unroll
            for (int j = 0; j < 8; ++j) o[j] = (_Float16)(v[c][j] * inv);
            *(half8*)(s + col0) = o;
        }
    }
}

// ---------------- launch ----------------
extern "C" void kernel_launch(void* const* d_in, const int* in_sizes, int n_in,
                              void* d_out, int out_size, void* d_ws, size_t ws_size,
                              hipStream_t stream) {
    const float* x  = (const float*)d_in[0];
    const float* Wq = (const float*)d_in[1];
    const float* Wk = (const float*)d_in[2];
    const float* Wv = (const float*)d_in[3];
    float* out = (float*)d_out;

    const size_t XB = (size_t)TB * TT * TD; // 33.5M elems

    // d_out doubles as scratch: x16 lo half, K hi half (dead before PV overwrites).
    _Float16* x16 = (_Float16*)d_out;
    _Float16* Kh  = (_Float16*)d_out + XB;

    char* ws = (char*)d_ws;
    size_t off = 0;
    auto carve = [&](size_t bytes) { char* p = ws + off; off = (off + bytes + 255) & ~(size_t)255; return p; };
    _Float16* wqt = (_Float16*)carve((size_t)TD * TD * 2); // wqt & wkt contiguous:
    _Float16* wkt = (_Float16*)carve((size_t)TD * TD * 2); //   [Wq^T ; Wk^T] = B [2048,1024]
    _Float16* wvt = (_Float16*)carve((size_t)TD * TD * 2);
    _Float16* Qh  = (_Float16*)carve(XB * 2);   // [B*T][1024]
    _Float16* Vt  = (_Float16*)carve(XB * 2);   // [B][1024][2048]

    const size_t CH = (size_t)TT * TT * 2;      // 8.39 MB / batch
    int NB = 16;
    while (NB > 1 && off + (size_t)NB * CH > ws_size) NB >>= 1;
    _Float16* Sc = (_Float16*)carve((size_t)NB * CH);

    // 1. x -> f16
    cvt_f32_f16<<<2048, 256, 0, stream>>>(x, x16, (long)XB);
    // 2. W^T f16
    transpose_cvt_w<<<dim3(32, 32), dim3(32, 8), 0, stream>>>(Wq, wqt);
    transpose_cvt_w<<<dim3(32, 32), dim3(32, 8), 0, stream>>>(Wk, wkt);
    transpose_cvt_w<<<dim3(32, 32), dim3(32, 8), 0, stream>>>(Wv, wvt);

    // 3. fused [Q|K] = x @ [Wq|Wk] : M=32768 (128 tiles), N=2048 (8 tiles);
    //    epilogue routes cols <1024 -> Qh, >=1024 -> Kh (d_out hi).
    gemm256<3><<<dim3(128 * 8, 1), 512, 0, stream>>>(x16, wqt, Qh, Kh, TD, TD, TD, TD,
                                                     0, 0, 0, 8, 128, 0);
    // 4. Vt[b] = (x[b] @ Wv)^T : M=1024 (4), N=2048 (8)
    gemm256<0><<<dim3(4 * 8, TB), 512, 0, stream>>>(wvt, x16, Vt, nullptr, TD, TD, TD, TT,
                                                    0, (long)TT * TD, (long)TD * TT, 8, 4, 0);

    // 5. per chunk of NB batches
    for (int cb = 0; cb < TB; cb += NB) {
        // S = Q K^T, lower-tri 256-tiles (36/batch), f16
        gemm256<1><<<dim3(36, NB), 512, 0, stream>>>(Qh + (size_t)cb * TT * TD,
                                                     Kh + (size_t)cb * TT * TD, Sc, nullptr,
                                                     TD, TD, TD, TT,
                                                     (long)TT * TD, (long)TT * TD, (long)TT * TT, 8, 8, 0);
        // causal softmax, in-place, wave-per-row (4 rows/block)
        softmax_rows_f16<<<NB * TT / 4, 256, 0, stream>>>(Sc, TT);
        // O = P @ V^T : 1D LPT grid (heavy ti first), K trimmed causally
        gemm256<2><<<dim3(NB * 32, 1), 512, 0, stream>>>(Sc, Vt + (size_t)cb * TD * TT,
                                                         out + (size_t)cb * TT * TD, nullptr, TT,
                                                         TT, TT, TD,
                                                         (long)TT * TT, (long)TD * TT, (long)TT * TD, 4, 8, NB);
    }
}